// Round 19
// baseline (269.824 us; speedup 1.0000x reference)
//
#include <hip/hip_runtime.h>
#include <math.h>

#define B_ 8192
#define D_ 4096
#define K_ 64
#define EPSF 1e-8f
#define LN2F 0.69314718056f
#define ENT_GRID 2048
#define SPLITS 16  // class-sum splits per class per tensor

typedef float f32x4 __attribute__((ext_vector_type(4)));
typedef unsigned short u16x4 __attribute__((ext_vector_type(4)));

__device__ __forceinline__ unsigned short f2bf(float f) {
  unsigned int b = __float_as_uint(f);
  b += 0x7FFF + ((b >> 16) & 1);  // round-to-nearest-even
  return (unsigned short)(b >> 16);
}

// ---------------- kernels ----------------

// zero counts[64] + sd1[64] + sd8[64] (contiguous 192 words)
__global__ void k_init(int* __restrict__ z) {
  if (threadIdx.x < 192) z[threadIdx.x] = 0;
}

// one wave per row: label + within-class rank (for the permuted destination)
__global__ void k_labels(const float* __restrict__ probs, int* __restrict__ labels,
                         int* __restrict__ wci, int* __restrict__ counts) {
  int row = blockIdx.x * 4 + (threadIdx.x >> 6);
  int lane = threadIdx.x & 63;
  float p = probs[(size_t)row * K_ + lane];
  unsigned long long m = __ballot(p > 0.5f);
  if (lane == 0) {
    int k = __ffsll(m) - 1;
    int kk = (k >= 0) ? k : 0;
    labels[row] = kk;
    wci[row] = atomicAdd(&counts[kk], 1);
  }
}

// exclusive prefix over counts -> base[k]
__global__ void k_prefix(const int* __restrict__ counts, int* __restrict__ base) {
  int k = threadIdx.x;  // 64 threads
  int s = 0;
  for (int j = 0; j < K_; ++j) s += (j < k) ? counts[j] : 0;
  base[k] = s;
}

// block per row, SEQUENTIAL read (proven 6.4 TB/s shape): norm-reduce, then
// write bf16(w*row) to the class-grouped position base[lb]+rank (8KB posted
// write). sd atomic once per block.
__global__ __launch_bounds__(256) void k_normpermute(const float* __restrict__ acts,
                                                     const int* __restrict__ labels,
                                                     const int* __restrict__ wci,
                                                     const int* __restrict__ base,
                                                     unsigned short* __restrict__ bperm,
                                                     float* __restrict__ sd) {
  __shared__ float lds[4];
  __shared__ float sw;
  int row = blockIdx.x;
  int t = threadIdx.x;
  const f32x4* rp = (const f32x4*)(acts + (size_t)row * D_);
  f32x4 v0 = rp[t];
  f32x4 v1 = rp[t + 256];
  f32x4 v2 = rp[t + 512];
  f32x4 v3 = rp[t + 768];
  float s = v0.x * v0.x + v0.y * v0.y + v0.z * v0.z + v0.w * v0.w;
  s += v1.x * v1.x + v1.y * v1.y + v1.z * v1.z + v1.w * v1.w;
  s += v2.x * v2.x + v2.y * v2.y + v2.z * v2.z + v2.w * v2.w;
  s += v3.x * v3.x + v3.y * v3.y + v3.z * v3.z + v3.w * v3.w;
#pragma unroll
  for (int o = 32; o > 0; o >>= 1) s += __shfl_down(s, o);
  if ((t & 63) == 0) lds[t >> 6] = s;
  __syncthreads();
  if (t == 0) {
    float stot = lds[0] + lds[1] + lds[2] + lds[3];
    float w = 1.0f / fmaxf(sqrtf(stot), EPSF);
    sw = w;
    atomicAdd(&sd[labels[row]], stot * w * w);
  }
  __syncthreads();
  float w = sw;
  int dst = base[labels[row]] + wci[row];
  unsigned short* brow = bperm + (size_t)dst * D_;
#define CVTSTORE(V, OFF)              \
  {                                   \
    u16x4 u_;                         \
    u_.x = f2bf(w * V.x);             \
    u_.y = f2bf(w * V.y);             \
    u_.z = f2bf(w * V.z);             \
    u_.w = f2bf(w * V.w);             \
    *(u16x4*)(brow + 4 * (OFF)) = u_; \
  }
  CVTSTORE(v0, t)
  CVTSTORE(v1, t + 256)
  CVTSTORE(v2, t + 512)
  CVTSTORE(v3, t + 768)
#undef CVTSTORE
}

#define GLOAD(X0, X1, ROW)                                       \
  {                                                              \
    const uint4* rp_ = (const uint4*)(bperm + (size_t)(ROW)*D_); \
    X0 = rp_[t];                                                 \
    X1 = rp_[t + 256];                                           \
  }

#define GCONS(X0, X1)                                          \
  {                                                            \
    unsigned int uu[8] = {X0.x, X0.y, X0.z, X0.w,              \
                          X1.x, X1.y, X1.z, X1.w};             \
    _Pragma("unroll") for (int q = 0; q < 8; ++q) {            \
      acc[2 * q] += __uint_as_float(uu[q] << 16);              \
      acc[2 * q + 1] += __uint_as_float(uu[q] & 0xFFFF0000u);  \
    }                                                          \
  }

// Class-sum over the permuted bf16 tensor: class k's rows are CONTIGUOUS at
// [base[k], base[k]+cnt[k]) -> fully sequential reads, L3-hot (just written).
// r16's verified bf16 accumulate body, 2-row register double buffer.
__global__ __launch_bounds__(256) void k_classsum(const unsigned short* __restrict__ bperm,
                                                  const int* __restrict__ counts,
                                                  const int* __restrict__ base,
                                                  float* __restrict__ Cpart) {
  int g = blockIdx.x;  // 0..1023
  int k = g & 63;
  int split = g >> 6;  // 0..15
  int t = threadIdx.x;
  int cnt = counts[k];
  int beg = base[k] + (cnt * split) / SPLITS;
  int end = base[k] + (cnt * (split + 1)) / SPLITS;
  float acc[16];
#pragma unroll
  for (int j = 0; j < 16; ++j) acc[j] = 0.f;
  uint4 a0, a1, b0, b1;
  int r = beg;
  if (end > beg) {
    GLOAD(a0, a1, r);
    for (; r + 2 <= end; r += 2) {
      GLOAD(b0, b1, r + 1);
      GCONS(a0, a1);
      if (r + 2 < end) GLOAD(a0, a1, r + 2);
      GCONS(b0, b1);
    }
    if (r < end) GCONS(a0, a1);
  }
  // acc[j] -> col 8t+j (j<8), col 2048+8t+(j-8) (j>=8)  [r16-verified mapping]
  float* cp = Cpart + ((size_t)split * K_ + k) * D_;
  *(f32x4*)(cp + 8 * t) = *(f32x4*)&acc[0];
  *(f32x4*)(cp + 8 * t + 4) = *(f32x4*)&acc[4];
  *(f32x4*)(cp + 2048 + 8 * t) = *(f32x4*)&acc[8];
  *(f32x4*)(cp + 2048 + 8 * t + 4) = *(f32x4*)&acc[12];
}

__device__ __forceinline__ float ent1(float p) {
  p = fminf(fmaxf(p, EPSF), 1.0f - EPSF);
  float q = 1.0f - p;
  float lp = __builtin_amdgcn_logf(p);  // v_log_f32: log2
  float lq = __builtin_amdgcn_logf(fmaxf(q, 1e-38f));
  return -(p * lp + q * lq);
}

__device__ __forceinline__ float ent4(f32x4 v) {
  return ent1(v.x) + ent1(v.y) + ent1(v.z) + ent1(v.w);
}

// binary entropy over both masks; plain loads, 16 in flight (r8-proven ~50us)
__global__ __launch_bounds__(256) void k_entropy(const f32x4* __restrict__ m1,
                                                 const f32x4* __restrict__ m8,
                                                 double* __restrict__ entpart) {
  __shared__ float lds[8];
  const int CHUNK = (B_ * D_ / 4) / ENT_GRID;  // 4096 f32x4 per block per mask
  int base = blockIdx.x * CHUNK;
  int t = threadIdx.x;
  float s1 = 0.f, s8 = 0.f;
#pragma unroll
  for (int o = 0; o < 2; ++o) {
    f32x4 a[8], b[8];
#pragma unroll
    for (int j = 0; j < 8; ++j) {
      int idx = base + t + (o * 8 + j) * 256;
      a[j] = m1[idx];
      b[j] = m8[idx];
    }
#pragma unroll
    for (int j = 0; j < 8; ++j) {
      s1 += ent4(a[j]);
      s8 += ent4(b[j]);
    }
  }
#pragma unroll
  for (int o = 32; o > 0; o >>= 1) {
    s1 += __shfl_down(s1, o);
    s8 += __shfl_down(s8, o);
  }
  int wid = t >> 6;
  if ((t & 63) == 0) { lds[wid] = s1; lds[4 + wid] = s8; }
  __syncthreads();
  if (t == 0) {
    float t1 = lds[0] + lds[1] + lds[2] + lds[3];
    float t8 = lds[4] + lds[5] + lds[6] + lds[7];
    entpart[blockIdx.x]            = (double)(t1 * LN2F);
    entpart[ENT_GRID + blockIdx.x] = (double)(t8 * LN2F);
  }
}

// mSm partials: 512 blocks; b<256 -> tensor1, else tensor8. k=b>>2, quarter q=b&3.
__global__ __launch_bounds__(256) void k_msm(const float* __restrict__ Cpart1,
                                             const float* __restrict__ Cpart8,
                                             float* __restrict__ msp1,
                                             float* __restrict__ msp8) {
  __shared__ float lds[4];
  int b = blockIdx.x;
  const float* Cpart = (b < 256) ? Cpart1 : Cpart8;
  float* msp = (b < 256) ? msp1 : msp8;
  b &= 255;
  int k = b >> 2;
  int q = b & 3;
  int t = threadIdx.x;
  int col = q * 1024 + 4 * t;
  f32x4 c = 0.f;
#pragma unroll
  for (int s = 0; s < SPLITS; ++s)
    c += *(const f32x4*)(Cpart + ((size_t)s * K_ + k) * D_ + col);
  float sq = c.x * c.x + c.y * c.y + c.z * c.z + c.w * c.w;
#pragma unroll
  for (int o = 32; o > 0; o >>= 1) sq += __shfl_down(sq, o);
  if ((t & 63) == 0) lds[t >> 6] = sq;
  __syncthreads();
  if (t == 0) msp[blockIdx.x & 255] = lds[0] + lds[1] + lds[2] + lds[3];
}

__global__ void k_final(const double* __restrict__ entpart, const int* __restrict__ counts,
                        const float* __restrict__ sd1, const float* __restrict__ sd8,
                        const float* __restrict__ msp1, const float* __restrict__ msp8,
                        float* __restrict__ out) {
  __shared__ double dl[8];
  int t = threadIdx.x;
  double e1 = 0.0, e8 = 0.0;
  for (int i = t; i < ENT_GRID; i += 256) {
    e1 += entpart[i];
    e8 += entpart[ENT_GRID + i];
  }
#pragma unroll
  for (int o = 32; o > 0; o >>= 1) {
    e1 += __shfl_down(e1, o);
    e8 += __shfl_down(e8, o);
  }
  int wid = t >> 6;
  if ((t & 63) == 0) { dl[wid] = e1; dl[4 + wid] = e8; }
  __syncthreads();
  float pcm1 = 0.f, pcm8 = 0.f, valid = 0.f;
  if (t < K_) {
    float mSm1 = msp1[t * 4] + msp1[t * 4 + 1] + msp1[t * 4 + 2] + msp1[t * 4 + 3];
    float mSm8 = msp8[t * 4] + msp8[t * 4 + 1] + msp8[t * 4 + 2] + msp8[t * 4 + 3];
    float n = (float)counts[t];
    bool v = (n >= 2.0f);
    float np = fmaxf(0.5f * n * (n - 1.0f), 1.0f);
    valid = v ? 1.0f : 0.f;
    pcm1 = v ? 0.5f * (mSm1 - sd1[t]) / np : 0.f;
    pcm8 = v ? 0.5f * (mSm8 - sd8[t]) / np : 0.f;
  }
#pragma unroll
  for (int o = 32; o > 0; o >>= 1) {
    pcm1 += __shfl_down(pcm1, o);
    pcm8 += __shfl_down(pcm8, o);
    valid += __shfl_down(valid, o);
  }
  if (t == 0) {
    double etot1 = dl[0] + dl[1] + dl[2] + dl[3];
    double etot8 = dl[4] + dl[5] + dl[6] + dl[7];
    float sp1 = (float)(etot1 / (double)((long long)B_ * D_));
    float sp8 = (float)(etot8 / (double)((long long)B_ * D_));
    float cs1 = (valid > 0.f) ? pcm1 / fmaxf(valid, 1.0f) : 0.f;
    float cs8 = (valid > 0.f) ? pcm8 / fmaxf(valid, 1.0f) : 0.f;
    float sim1 = -cs1, sim8 = -cs8;
    out[0] = sim1 + sim8 + 0.001f * (sp1 + sp8);
    out[1] = sim1;
    out[2] = sim8;
    out[3] = sp1;
    out[4] = sp8;
  }
}

// ---------------- launcher ----------------
// ws layout (bytes):
//   0         : double entpart[2][2048]   32768
//   32768     : int    labels[B]          32768
//   65536     : int    wci[B]             32768
//   98304     : int    counts[64]         256  \
//   98560     : float  sd1[64]            256   } zeroed together (192 words)
//   98816     : float  sd8[64]            256  /
//   99072     : int    base[64]           256
//   99328     : float  msp1[256]          1024
//   100352    : float  msp8[256]          1024
//   131072    : float  Cpart1[16][K][D]   16777216
//   16908288  : float  Cpart8[16][K][D]   16777216
//   33685504  : ushort bperm1[B][D]       67108864
//   100794368 : ushort bperm8[B][D]       67108864
//   total ~168 MB (ws_size observed ~539 MB)

extern "C" void kernel_launch(void* const* d_in, const int* in_sizes, int n_in,
                              void* d_out, int out_size, void* d_ws, size_t ws_size,
                              hipStream_t stream) {
  const float* probs = (const float*)d_in[0];
  const float* a1 = (const float*)d_in[1];
  const float* a8 = (const float*)d_in[2];
  const float* m1 = (const float*)d_in[3];
  const float* m8 = (const float*)d_in[4];
  float* out = (float*)d_out;
  char* ws = (char*)d_ws;

  double* entpart = (double*)(ws + 0);
  int* labels = (int*)(ws + 32768);
  int* wci = (int*)(ws + 65536);
  int* counts = (int*)(ws + 98304);
  float* sd1 = (float*)(ws + 98560);
  float* sd8 = (float*)(ws + 98816);
  int* base = (int*)(ws + 99072);
  float* msp1 = (float*)(ws + 99328);
  float* msp8 = (float*)(ws + 100352);
  float* Cpart1 = (float*)(ws + 131072);
  float* Cpart8 = (float*)(ws + 16908288);
  unsigned short* bperm1 = (unsigned short*)(ws + 33685504);
  unsigned short* bperm8 = (unsigned short*)(ws + 100794368);

  k_init<<<1, 256, 0, stream>>>(counts);
  k_labels<<<B_ / 4, 256, 0, stream>>>(probs, labels, wci, counts);
  k_prefix<<<1, 64, 0, stream>>>(counts, base);
  // tensor 1: sequential read + class-grouped bf16 write, then sequential
  // (L3-hot) class-sum — no random reads anywhere
  k_normpermute<<<B_, 256, 0, stream>>>(a1, labels, wci, base, bperm1, sd1);
  k_classsum<<<K_ * SPLITS, 256, 0, stream>>>(bperm1, counts, base, Cpart1);
  // tensor 8
  k_normpermute<<<B_, 256, 0, stream>>>(a8, labels, wci, base, bperm8, sd8);
  k_classsum<<<K_ * SPLITS, 256, 0, stream>>>(bperm8, counts, base, Cpart8);
  k_entropy<<<ENT_GRID, 256, 0, stream>>>((const f32x4*)m1, (const f32x4*)m8, entpart);
  k_msm<<<512, 256, 0, stream>>>(Cpart1, Cpart8, msp1, msp8);
  k_final<<<1, 256, 0, stream>>>(entpart, counts, sd1, sd8, msp1, msp8, out);
}